// Round 3
// baseline (267.670 us; speedup 1.0000x reference)
//
#include <hip/hip_runtime.h>

#define IN_SIZE 224
#define KER 5
#define IN_CH 16
#define OUT_CH 64
#define NH 220
#define NB_TILES (NH * NH)       // 48400
#define XCH (IN_SIZE * IN_SIZE)  // 50176
#define OUT_PLANE NB_TILES
#define LR_OVER_NB ((float)(0.005 / 48400.0))
#define GAMMA_F 0.99f
#define ONE_MINUS_GAMMA 0.01f
#define EPS_F 0.01f

#define TS 64
#define XT 68  // TS + KER - 1

// ---------------- Kernel 1: conv, 64x64 tile, 4x4 micro-tile, 2 oc/block ----------------
__global__ __launch_bounds__(256) void conv_kernel(const float* __restrict__ x,
                                                   const float* __restrict__ W,
                                                   float* __restrict__ out) {
    __shared__ float xs[XT * XT];  // 18.5 KB
    const int tx = threadIdx.x & 15;
    const int ty = threadIdx.x >> 4;
    const int ti = blockIdx.y * TS;
    const int tj = blockIdx.x * TS;
    const int oc0 = blockIdx.z * 2;

    float acc0[16], acc1[16];
#pragma unroll
    for (int i = 0; i < 16; i++) { acc0[i] = 0.f; acc1[i] = 0.f; }

    const float* W0 = W + oc0 * 400;
    const float* W1 = W0 + 400;

    for (int c = 0; c < IN_CH; c++) {
        __syncthreads();
        for (int s = threadIdx.x; s < XT * 17; s += 256) {
            int row = s / 17;
            int q = s - row * 17;
            int gy = ti + row, gx = tj + 4 * q;
            float4 v = make_float4(0.f, 0.f, 0.f, 0.f);
            if (gy < IN_SIZE && gx < IN_SIZE)
                v = *(const float4*)(x + c * XCH + gy * IN_SIZE + gx);
            *(float4*)(xs + row * XT + 4 * q) = v;
        }
        __syncthreads();

        float w0[25], w1[25];
#pragma unroll
        for (int q = 0; q < 25; q++) { w0[q] = W0[c * 25 + q]; w1[q] = W1[c * 25 + q]; }

#pragma unroll
        for (int rr = 0; rr < 8; rr++) {
            int row = 4 * ty + rr;
            float xr[8];
            ((float4*)xr)[0] = *(const float4*)(xs + row * XT + 4 * tx);
            ((float4*)xr)[1] = *(const float4*)(xs + row * XT + 4 * tx + 4);
#pragma unroll
            for (int dy = 0; dy < 4; dy++) {
                int ki = rr - dy;
                if (ki >= 0 && ki <= 4) {
#pragma unroll
                    for (int kj = 0; kj < 5; kj++) {
                        float wv0 = w0[ki * 5 + kj];
                        float wv1 = w1[ki * 5 + kj];
#pragma unroll
                        for (int dx = 0; dx < 4; dx++) {
                            acc0[dy * 4 + dx] = fmaf(wv0, xr[dx + kj], acc0[dy * 4 + dx]);
                            acc1[dy * 4 + dx] = fmaf(wv1, xr[dx + kj], acc1[dy * 4 + dx]);
                        }
                    }
                }
            }
        }
    }

    int gj = tj + 4 * tx;
    if (gj < NH) {
#pragma unroll
        for (int dy = 0; dy < 4; dy++) {
            int gi = ti + 4 * ty + dy;
            if (gi < NH) {
                *(float4*)(out + oc0 * OUT_PLANE + gi * NH + gj) =
                    make_float4(acc0[dy * 4], acc0[dy * 4 + 1], acc0[dy * 4 + 2], acc0[dy * 4 + 3]);
                *(float4*)(out + (oc0 + 1) * OUT_PLANE + gi * NH + gj) =
                    make_float4(acc1[dy * 4], acc1[dy * 4 + 1], acc1[dy * 4 + 2], acc1[dy * 4 + 3]);
            }
        }
    }
}

// ---------------- Kernel 2: inhibition, register-resident, streaming ----------------
__global__ __launch_bounds__(128) void inhib_kernel(float* __restrict__ out) {
    int p = blockIdx.x * 128 + threadIdx.x;
    if (p >= NB_TILES) return;
    float v[OUT_CH];
    float m = 0.f;
#pragma unroll
    for (int oc = 0; oc < OUT_CH; oc++) {
        float t = out[oc * OUT_PLANE + p];
        t = fmaxf(t, 0.f);
        v[oc] = t;
        m = fmaxf(m, t);
    }
    float inv = 1.f / (m + 1e-9f);
#pragma unroll
    for (int oc = 0; oc < OUT_CH; oc++) {
        float t = v[oc] * inv;
        float t2 = t * t;
        out[oc * OUT_PLANE + p] = t2 * t2 * t;
    }
}

// ---------------- Kernel 3: colsum, split 4-way per channel ----------------
__global__ __launch_bounds__(256) void colsum_kernel(const float* __restrict__ y,
                                                     float* __restrict__ colsum) {
    int oc = blockIdx.x >> 2;
    int part = blockIdx.x & 3;
    const float* row = y + oc * OUT_PLANE;
    int p0 = part * 12100, p1 = p0 + 12100;
    float s = 0.f;
    for (int p = p0 + threadIdx.x; p < p1; p += 256) s += row[p];
    for (int off = 32; off; off >>= 1) s += __shfl_down(s, off);
    __shared__ float sm[4];
    int lane = threadIdx.x & 63, wv = threadIdx.x >> 6;
    if (lane == 0) sm[wv] = s;
    __syncthreads();
    if (threadIdx.x == 0) atomicAdd(colsum + oc, sm[0] + sm[1] + sm[2] + sm[3]);
}

// ---------------- Kernel 4: y^T y, float4 along k, no LDS ----------------
#define GCHUNK 128
__global__ __launch_bounds__(256) void gram_kernel(const float* __restrict__ y,
                                                   float* __restrict__ yty) {
    const int ta = threadIdx.x >> 4;  // 0..15
    const int tb = threadIdx.x & 15;  // 0..15
    int p0 = blockIdx.x * GCHUNK;
    int pend = p0 + GCHUNK;
    if (pend > NB_TILES) pend = NB_TILES;
    const float* ya = y + 4 * ta * OUT_PLANE;
    const float* yb = y + 4 * tb * OUT_PLANE;

    float acc[16];
#pragma unroll
    for (int i = 0; i < 16; i++) acc[i] = 0.f;

    int p = p0;
    for (; p + 4 <= pend; p += 4) {
        float4 av[4], bv[4];
#pragma unroll
        for (int i = 0; i < 4; i++) av[i] = *(const float4*)(ya + i * OUT_PLANE + p);
#pragma unroll
        for (int i = 0; i < 4; i++) bv[i] = *(const float4*)(yb + i * OUT_PLANE + p);
#pragma unroll
        for (int i = 0; i < 4; i++) {
#pragma unroll
            for (int j = 0; j < 4; j++) {
                float s = acc[i * 4 + j];
                s = fmaf(av[i].x, bv[j].x, s);
                s = fmaf(av[i].y, bv[j].y, s);
                s = fmaf(av[i].z, bv[j].z, s);
                s = fmaf(av[i].w, bv[j].w, s);
                acc[i * 4 + j] = s;
            }
        }
    }
    for (; p < pend; p++) {
#pragma unroll
        for (int i = 0; i < 4; i++) {
            float a = ya[i * OUT_PLANE + p];
#pragma unroll
            for (int j = 0; j < 4; j++) acc[i * 4 + j] = fmaf(a, yb[j * OUT_PLANE + p], acc[i * 4 + j]);
        }
    }
#pragma unroll
    for (int i = 0; i < 4; i++)
#pragma unroll
        for (int j = 0; j < 4; j++)
            atomicAdd(yty + (4 * ta + i) * OUT_CH + 4 * tb + j, acc[i * 4 + j]);
}

// ---------------- Kernel 5: y^T xf ----------------
__global__ __launch_bounds__(256) void ytxf_kernel(const float* __restrict__ y,
                                                   const float* __restrict__ x,
                                                   float* __restrict__ Mpart) {
    const int c = blockIdx.x;
    const int og = blockIdx.y * 4;
    const int half = blockIdx.z;
    const int row0 = half * 110;

    float acc[4][25];
#pragma unroll
    for (int t = 0; t < 4; t++)
#pragma unroll
        for (int q = 0; q < 25; q++) acc[t][q] = 0.f;

    const float* xc = x + c * XCH;
    for (int ch = threadIdx.x; ch < 110 * 55; ch += 256) {
        int ii = ch / 55;
        int j = 4 * (ch - ii * 55);
        int i = row0 + ii;
        int p = i * NH + j;
        float4 yv[4];
#pragma unroll
        for (int t = 0; t < 4; t++) yv[t] = *(const float4*)(y + (og + t) * OUT_PLANE + p);
        float xr[5][8];
#pragma unroll
        for (int ki = 0; ki < 5; ki++) {
            ((float4*)xr[ki])[0] = *(const float4*)(xc + (i + ki) * IN_SIZE + j);
            ((float4*)xr[ki])[1] = *(const float4*)(xc + (i + ki) * IN_SIZE + j + 4);
        }
#pragma unroll
        for (int t = 0; t < 4; t++) {
            float yv4[4] = {yv[t].x, yv[t].y, yv[t].z, yv[t].w};
#pragma unroll
            for (int ki = 0; ki < 5; ki++) {
#pragma unroll
                for (int kj = 0; kj < 5; kj++) {
                    float a = acc[t][ki * 5 + kj];
                    a = fmaf(yv4[0], xr[ki][kj], a);
                    a = fmaf(yv4[1], xr[ki][kj + 1], a);
                    a = fmaf(yv4[2], xr[ki][kj + 2], a);
                    a = fmaf(yv4[3], xr[ki][kj + 3], a);
                    acc[t][ki * 5 + kj] = a;
                }
            }
        }
    }

    __shared__ float sred[4 * 100];
    const int lane = threadIdx.x & 63, wv = threadIdx.x >> 6;
#pragma unroll
    for (int t = 0; t < 4; t++) {
#pragma unroll
        for (int q = 0; q < 25; q++) {
            float v = acc[t][q];
            for (int off = 32; off; off >>= 1) v += __shfl_down(v, off);
            if (lane == 0) sred[wv * 100 + t * 25 + q] = v;
        }
    }
    __syncthreads();
    if (threadIdx.x < 100) {
        float v = sred[threadIdx.x] + sred[100 + threadIdx.x] + sred[200 + threadIdx.x] +
                  sred[300 + threadIdx.x];
        int t = threadIdx.x / 25, q = threadIdx.x - 25 * t;
        Mpart[half * 25600 + (og + t) * 400 + c * 25 + q] = v;
    }
}

// ---------------- Kernel 6: exp_new + gfp ----------------
__global__ void finalize_stats(const float* __restrict__ exp_avg,
                               const float* __restrict__ colsum,
                               float* __restrict__ exp_out, float* __restrict__ gfp) {
    int o = threadIdx.x;
    float e = GAMMA_F * exp_avg[o] + ONE_MINUS_GAMMA * (colsum[o] / (float)NB_TILES);
    float s = e;
    for (int off = 32; off; off >>= 1) s += __shfl_down(s, off);
    s = __shfl(s, 0);
    float A = e / (s / (float)OUT_CH);
    float gp = EPS_F * tanhf(-EPS_F * (A - 1.f)) + 1.f;
    exp_out[o] = e;
    gfp[o] = gp;
}

// ---------------- Kernel 7: Wfinal ----------------
__global__ __launch_bounds__(256) void finalize_w_kernel(const float* __restrict__ W,
                                                         const float* __restrict__ yty,
                                                         const float* __restrict__ Mpart,
                                                         const float* __restrict__ gfp,
                                                         float* __restrict__ Wout) {
    int idx = blockIdx.x * 256 + threadIdx.x;
    int o = idx / 400;
    int q = idx - o * 400;
    float dot = 0.f;
#pragma unroll 8
    for (int k = 0; k < OUT_CH; k++) dot = fmaf(yty[o * 64 + k], W[k * 400 + q], dot);
    float M = Mpart[idx] + Mpart[25600 + idx];
    float w = W[idx] + LR_OVER_NB * (M - dot);
    w = fmaxf(w, 0.f);
    float gp = gfp[o];
    float pos = (w > 0.f ? w : 0.f) * gp;
    float neg = (w < 0.f ? w : 0.f) / gp;
    Wout[idx] = pos + neg;
}

extern "C" void kernel_launch(void* const* d_in, const int* in_sizes, int n_in,
                              void* d_out, int out_size, void* d_ws, size_t ws_size,
                              hipStream_t stream) {
    const float* x = (const float*)d_in[0];
    const float* W = (const float*)d_in[1];
    const float* exp_avg = (const float*)d_in[2];
    float* out = (float*)d_out;

    float* ws = (float*)d_ws;
    float* yty = ws;             // 4096
    float* colsum = ws + 4096;   // 64
    float* gfp = ws + 4160;      // 64
    float* Mpart = ws + 4224;    // 2 * 25600

    float* Wout = out + OUT_CH * OUT_PLANE;
    float* expout = Wout + OUT_CH * IN_CH * KER * KER;

    hipMemsetAsync(ws, 0, (4096 + 64) * sizeof(float), stream);  // yty + colsum

    conv_kernel<<<dim3(4, 4, 32), 256, 0, stream>>>(x, W, out);
    inhib_kernel<<<(NB_TILES + 127) / 128, 128, 0, stream>>>(out);
    colsum_kernel<<<256, 256, 0, stream>>>(out, colsum);
    gram_kernel<<<(NB_TILES + GCHUNK - 1) / GCHUNK, 256, 0, stream>>>(out, yty);
    ytxf_kernel<<<dim3(16, 16, 2), 256, 0, stream>>>(out, x, Mpart);
    finalize_stats<<<1, 64, 0, stream>>>(exp_avg, colsum, expout, gfp);
    finalize_w_kernel<<<100, 256, 0, stream>>>(W, yty, Mpart, gfp, Wout);
}

// Round 4
// 266.597 us; speedup vs baseline: 1.0040x; 1.0040x over previous
//
#include <hip/hip_runtime.h>
#include <stdint.h>

#define IN_SIZE 224
#define KER 5
#define IN_CH 16
#define OUT_CH 64
#define NH 220
#define NB_TILES (NH * NH)       // 48400
#define XCH (IN_SIZE * IN_SIZE)  // 50176
#define OUT_PLANE NB_TILES
#define YSTRIDE 49280            // 220*224: bf16 y, row-padded to 224, K-dim
#define LR_OVER_NB ((float)(0.005 / 48400.0))
#define GAMMA_F 0.99f
#define ONE_MINUS_GAMMA 0.01f
#define EPS_F 0.01f

typedef __attribute__((ext_vector_type(8))) short short8;
typedef __attribute__((ext_vector_type(4))) float floatx4;

__device__ inline uint16_t f2bf(float f) {
    uint32_t u = __float_as_uint(f);
    return (uint16_t)((u + 0x7FFFu + ((u >> 16) & 1u)) >> 16);
}

// ---------------- Kernel 0: cast x to bf16 (+pads), zero y-pad columns ----------------
__global__ __launch_bounds__(256) void xcast_kernel(const float* __restrict__ x,
                                                    uint16_t* __restrict__ xb,
                                                    uint16_t* __restrict__ yb) {
    int t = blockIdx.x * 256 + threadIdx.x;  // 0..200703
    if (t < XCH * IN_CH / 4) {
        float4 v = ((const float4*)x)[t];
        ushort4 o;
        o.x = f2bf(v.x); o.y = f2bf(v.y); o.z = f2bf(v.z); o.w = f2bf(v.w);
        ((ushort4*)xb)[t] = o;
    }
    if (t < 16) {  // zero 64-elem tail pad of xb
        ushort4 z = {0, 0, 0, 0};
        ((ushort4*)(xb + XCH * IN_CH))[t] = z;
    }
    if (t < OUT_CH * NH) {  // zero y pad columns j=220..223 (4 = one ushort4)
        int o = t / NH, i = t - o * NH;
        ushort4 z = {0, 0, 0, 0};
        *(ushort4*)(yb + o * YSTRIDE + i * IN_SIZE + NH) = z;
    }
}

// ---------------- Kernel 1: conv, 64x64 tile, 4x4 micro-tile, 1 oc/block ----------------
__global__ __launch_bounds__(256) void conv_kernel(const float* __restrict__ x,
                                                   const float* __restrict__ W,
                                                   float* __restrict__ out) {
    __shared__ float xs[68 * 68];
    const int tx = threadIdx.x & 15;
    const int ty = threadIdx.x >> 4;
    const int ti = blockIdx.y * 64;
    const int tj = blockIdx.x * 64;
    const int oc = blockIdx.z;

    float acc[16];
#pragma unroll
    for (int i = 0; i < 16; i++) acc[i] = 0.f;
    const float* W0 = W + oc * 400;

    for (int c = 0; c < IN_CH; c++) {
        __syncthreads();
        for (int s = threadIdx.x; s < 68 * 17; s += 256) {
            int row = s / 17;
            int q = s - row * 17;
            int gy = ti + row, gx = tj + 4 * q;
            float4 v = make_float4(0.f, 0.f, 0.f, 0.f);
            if (gy < IN_SIZE && gx < IN_SIZE)
                v = *(const float4*)(x + c * XCH + gy * IN_SIZE + gx);
            *(float4*)(xs + row * 68 + 4 * q) = v;
        }
        __syncthreads();

        float w0[25];
#pragma unroll
        for (int q = 0; q < 25; q++) w0[q] = W0[c * 25 + q];

#pragma unroll
        for (int rr = 0; rr < 8; rr++) {
            int row = 4 * ty + rr;
            float xr[8];
            ((float4*)xr)[0] = *(const float4*)(xs + row * 68 + 4 * tx);
            ((float4*)xr)[1] = *(const float4*)(xs + row * 68 + 4 * tx + 4);
#pragma unroll
            for (int dy = 0; dy < 4; dy++) {
                int ki = rr - dy;
                if (ki >= 0 && ki <= 4) {
#pragma unroll
                    for (int kj = 0; kj < 5; kj++) {
                        float wv = w0[ki * 5 + kj];
#pragma unroll
                        for (int dx = 0; dx < 4; dx++)
                            acc[dy * 4 + dx] = fmaf(wv, xr[dx + kj], acc[dy * 4 + dx]);
                    }
                }
            }
        }
    }

    int gj = tj + 4 * tx;
    if (gj < NH) {
#pragma unroll
        for (int dy = 0; dy < 4; dy++) {
            int gi = ti + 4 * ty + dy;
            if (gi < NH)
                *(float4*)(out + oc * OUT_PLANE + gi * NH + gj) =
                    make_float4(acc[dy * 4], acc[dy * 4 + 1], acc[dy * 4 + 2], acc[dy * 4 + 3]);
        }
    }
}

// ---------------- Kernel 2: inhibition (in-place fp32) + bf16 y copy (padded) ----------------
__global__ __launch_bounds__(256) void inhib_kernel(float* __restrict__ out,
                                                    uint16_t* __restrict__ yb) {
    int p = blockIdx.x * 256 + threadIdx.x;
    if (p >= NB_TILES) return;
    int i = p / NH;
    int j = p - i * NH;
    float v[OUT_CH];
    float m = 0.f;
#pragma unroll
    for (int oc = 0; oc < OUT_CH; oc++) {
        float t = out[oc * OUT_PLANE + p];
        t = fmaxf(t, 0.f);
        v[oc] = t;
        m = fmaxf(m, t);
    }
    float inv = 1.f / (m + 1e-9f);
#pragma unroll
    for (int oc = 0; oc < OUT_CH; oc++) {
        float t = v[oc] * inv;
        float t2 = t * t;
        t = t2 * t2 * t;
        out[oc * OUT_PLANE + p] = t;
        yb[oc * YSTRIDE + i * IN_SIZE + j] = f2bf(t);
    }
}

// ---------------- Kernel 3: colsum (fp32-exact), 8-way split per channel ----------------
__global__ __launch_bounds__(256) void colsum_kernel(const float* __restrict__ y,
                                                     float* __restrict__ colsum) {
    int oc = blockIdx.x >> 3;
    int part = blockIdx.x & 7;
    const float* row = y + oc * OUT_PLANE;
    int p0 = part * 6050, p1 = p0 + 6050;
    float s = 0.f;
    for (int p = p0 + threadIdx.x; p < p1; p += 256) s += row[p];
    for (int off = 32; off; off >>= 1) s += __shfl_down(s, off);
    __shared__ float sm[4];
    int lane = threadIdx.x & 63, wv = threadIdx.x >> 6;
    if (lane == 0) sm[wv] = s;
    __syncthreads();
    if (threadIdx.x == 0) atomicAdd(colsum + oc, sm[0] + sm[1] + sm[2] + sm[3]);
}

// ---------------- Kernel 4: y^T y via bf16 MFMA 16x16x32, split-K ----------------
// grid (4, 55): blockIdx.x = a-row-group, blockIdx.y = k-chunk (28 steps of 32)
__global__ __launch_bounds__(256) void gram_kernel(const uint16_t* __restrict__ yb,
                                                   float* __restrict__ yty) {
    const int lane = threadIdx.x & 63;
    const int bg = threadIdx.x >> 6;  // b col-group = wave
    const int ag = blockIdx.x;
    const int l15 = lane & 15, kg = (lane >> 4) * 8;
    const uint16_t* pa = yb + (16 * ag + l15) * YSTRIDE + blockIdx.y * (28 * 32) + kg;
    const uint16_t* pb = yb + (16 * bg + l15) * YSTRIDE + blockIdx.y * (28 * 32) + kg;
    floatx4 acc = {0.f, 0.f, 0.f, 0.f};
    short8 a = *(const short8*)pa;
    short8 b = *(const short8*)pb;
    for (int s = 0; s < 27; s++) {
        pa += 32; pb += 32;
        short8 an = *(const short8*)pa;
        short8 bn = *(const short8*)pb;
        acc = __builtin_amdgcn_mfma_f32_16x16x32_bf16(a, b, acc, 0, 0, 0);
        a = an; b = bn;
    }
    acc = __builtin_amdgcn_mfma_f32_16x16x32_bf16(a, b, acc, 0, 0, 0);
    int row = 16 * ag + (lane >> 4) * 4;
    int col = 16 * bg + l15;
#pragma unroll
    for (int r = 0; r < 4; r++) atomicAdd(yty + (row + r) * OUT_CH + col, acc[r]);
}

// ---------------- Kernel 5: M = y^T xf via bf16 MFMA, split-K ----------------
// grid (25, 20): blockIdx.x = col-tile (16 of 400), blockIdx.y = k-chunk (77 steps)
// wave = row-group. B[k][n] = x[c][(i+ki)][(j+kj)] = xb[c*XCH + ki*224 + kj + k].
__global__ __launch_bounds__(256) void ytxf_kernel(const uint16_t* __restrict__ yb,
                                                   const uint16_t* __restrict__ xb,
                                                   float* __restrict__ M) {
    const int lane = threadIdx.x & 63;
    const int rg = threadIdx.x >> 6;
    const int cb = blockIdx.x;
    const int l15 = lane & 15, kg = (lane >> 4) * 8;
    const int n = 16 * cb + l15;          // 0..399
    const int c = n / 25;
    const int r = n - 25 * c;
    const int ki = r / 5, kj = r - 5 * (r / 5);
    const int idx = kj >> 1;
    const int sh = (kj & 1) * 16;

    const uint16_t* pa = yb + (16 * rg + l15) * YSTRIDE + blockIdx.y * (77 * 32) + kg;
    const uint16_t* pb = xb + c * XCH + ki * IN_SIZE + blockIdx.y * (77 * 32) + kg;

    floatx4 acc = {0.f, 0.f, 0.f, 0.f};
    for (int s = 0; s < 77; s++) {
        short8 a = *(const short8*)pa;
        uint32_t dw[7];
        *(uint4*)dw = *(const uint4*)pb;            // elems 0..7 (16B aligned)
        *(uint2*)(dw + 4) = *(const uint2*)(pb + 8);  // elems 8..11
        dw[6] = 0u;
        union { uint32_t u[4]; short8 s8; } bu;
#pragma unroll
        for (int t = 0; t < 4; t++)
            bu.u[t] = (uint32_t)((((uint64_t)dw[idx + t + 1] << 32) | dw[idx + t]) >> sh);
        acc = __builtin_amdgcn_mfma_f32_16x16x32_bf16(a, bu.s8, acc, 0, 0, 0);
        pa += 32; pb += 32;
    }
    int row = 16 * rg + (lane >> 4) * 4;
#pragma unroll
    for (int r2 = 0; r2 < 4; r2++) atomicAdd(M + (row + r2) * 400 + n, acc[r2]);
}

// ---------------- Kernel 6: exp_new + gfp ----------------
__global__ void finalize_stats(const float* __restrict__ exp_avg,
                               const float* __restrict__ colsum,
                               float* __restrict__ exp_out, float* __restrict__ gfp) {
    int o = threadIdx.x;
    float e = GAMMA_F * exp_avg[o] + ONE_MINUS_GAMMA * (colsum[o] / (float)NB_TILES);
    float s = e;
    for (int off = 32; off; off >>= 1) s += __shfl_down(s, off);
    s = __shfl(s, 0);
    float A = e / (s / (float)OUT_CH);
    float gp = EPS_F * tanhf(-EPS_F * (A - 1.f)) + 1.f;
    exp_out[o] = e;
    gfp[o] = gp;
}

// ---------------- Kernel 7: Wfinal ----------------
__global__ __launch_bounds__(256) void finalize_w_kernel(const float* __restrict__ W,
                                                         const float* __restrict__ yty,
                                                         const float* __restrict__ M,
                                                         const float* __restrict__ gfp,
                                                         float* __restrict__ Wout) {
    int idx = blockIdx.x * 256 + threadIdx.x;
    int o = idx / 400;
    int q = idx - o * 400;
    float dot = 0.f;
#pragma unroll 8
    for (int k = 0; k < OUT_CH; k++) dot = fmaf(yty[o * 64 + k], W[k * 400 + q], dot);
    float w = W[idx] + LR_OVER_NB * (M[idx] - dot);
    w = fmaxf(w, 0.f);
    float gp = gfp[o];
    float pos = (w > 0.f ? w : 0.f) * gp;
    float neg = (w < 0.f ? w : 0.f) / gp;
    Wout[idx] = pos + neg;
}

extern "C" void kernel_launch(void* const* d_in, const int* in_sizes, int n_in,
                              void* d_out, int out_size, void* d_ws, size_t ws_size,
                              hipStream_t stream) {
    const float* x = (const float*)d_in[0];
    const float* W = (const float*)d_in[1];
    const float* exp_avg = (const float*)d_in[2];
    float* out = (float*)d_out;

    float* wsf = (float*)d_ws;
    float* yty = wsf;              // 4096
    float* colsum = wsf + 4096;    // 64
    float* gfp = wsf + 4160;       // 64
    float* M = wsf + 4224;         // 25600
    uint16_t* ybf = (uint16_t*)((char*)d_ws + 29824 * sizeof(float));  // 64*49280
    uint16_t* xbf = ybf + OUT_CH * YSTRIDE;                            // 802816+64

    float* Wout = out + OUT_CH * OUT_PLANE;
    float* expout = Wout + OUT_CH * IN_CH * KER * KER;

    hipMemsetAsync(d_ws, 0, 29824 * sizeof(float), stream);  // yty|colsum|gfp|M

    xcast_kernel<<<784, 256, 0, stream>>>(x, xbf, ybf);
    conv_kernel<<<dim3(4, 4, 64), 256, 0, stream>>>(x, W, out);
    inhib_kernel<<<(NB_TILES + 255) / 256, 256, 0, stream>>>(out, ybf);
    colsum_kernel<<<512, 256, 0, stream>>>(out, colsum);
    gram_kernel<<<dim3(4, 55), 256, 0, stream>>>(ybf, yty);
    ytxf_kernel<<<dim3(25, 20), 256, 0, stream>>>(ybf, xbf, M);
    finalize_stats<<<1, 64, 0, stream>>>(exp_avg, colsum, expout, gfp);
    finalize_w_kernel<<<100, 256, 0, stream>>>(W, yty, M, gfp, Wout);
}